// Round 8
// baseline (180.578 us; speedup 1.0000x reference)
//
#include <hip/hip_runtime.h>

// NCC loss: five 9x9x9 box sums over (2,1,160,160,160) fp32 volumes, fused.
// Separable box filter; block owns a 16(W)x32(H) tile, streams 32 outputs
// along D. D-window in registers (ring[9][5], compile-time slot index).
//
// R8: two barrier-independent blocks per CU + wider LDS reads.
// Post-mortem R7: LDS *issue* arithmetic closes with the measured 90us
// (b32=5.8cyc, b128=12cyc -> ~5300 cyc/block-slice x40 = 88us), and VGPR
// 60-64 empirically pins residency at ~13-16 waves/CU (the ring's 45 regs).
// A single 16-wave block drains at every barrier with nothing to hide it.
// Changes:
//  - 512t blocks (8 waves), tile 16Wx32H: VGPR~64 budget -> 2 blocks/CU
//    co-resident; each block's compute fills the other's barrier drains.
//    Grid 10x5x10 = 500 = 2/CU exact. Phase-B H-redundancy stays 1.25;
//    staging redundancy 1.56->1.88 (FETCH +20%, HBM only ~17% -- cheap).
//  - float2-interleaved halo (R0 layout): phase B = 9 b64 reads per item
//    instead of 18 b32 -- halves the dominant read-issue count.
//  - keeps R7: reg-prefetch double-buffered staging (T14), DCHUNK 32,
//    float4+float packed row sums, fused finalize.
// d_ws: [0:8) double accumulator, [8:12) unsigned completion counter.

#define NB   2
#define NDIM 160
#define TW   16
#define TH   32
#define REW  24      // TW + 8 halo
#define REH  40      // TH + 8 halo
#define NPTS (REH * REW)          // 960 staged points
#define DCHUNK 32
#define NDCHUNK (NDIM / DCHUNK)   // 5
#define NSLICE (DCHUNK + 8)       // 40 real slices per block
#define NBLK ((NDIM/TW)*(NDIM/TH)*NB*NDCHUNK)   // 10*5*10 = 500
#define NTHR 512
#define SLICE_SZ (NDIM * NDIM)

__global__ __launch_bounds__(NTHR)
void ncc_main(const float* __restrict__ I, const float* __restrict__ J,
              double* __restrict__ out_acc, unsigned int* __restrict__ out_cnt,
              float* __restrict__ out) {
    const int t  = threadIdx.x;
    const int tx = t & 15;            // W within tile
    const int ty = t >> 4;            // H within tile
    const int w0 = blockIdx.x * TW;
    const int h0 = blockIdx.y * TH;
    const int b  = blockIdx.z / NDCHUNK;
    const int d0 = (blockIdx.z % NDCHUNK) * DCHUNK;

    const float* Ib = I + (size_t)b * NDIM * SLICE_SZ;
    const float* Jb = J + (size_t)b * NDIM * SLICE_SZ;

    // Double-buffered interleaved halo; row sums single-buffered (B->C by
    // barrier1, C->next-B by barrier2).
    __shared__ float2 sIJ[2][REH][REW + 1];   // 25-float2 row stride
    __shared__ float4 rs4[REH][TW + 1];       // row sums {I, J, I2, J2}
    __shared__ float  rss[REH][TW + 1];       // row sums IJ
    __shared__ double wsum[NTHR / 64];

    // Per-thread staging coords (960 items / 512 threads -> 2 slots,
    // slot1 active for t < 448). Precomputed once; reused every slice.
    const int e1 = t + NTHR;
    const int r0 = t / REW,  c0 = t - r0 * REW;
    const int r1 = e1 / REW, c1 = e1 - r1 * REW;
    const int h_0 = h0 - 4 + r0, w_0 = w0 - 4 + c0;
    const int h_1 = h0 - 4 + r1, w_1 = w0 - 4 + c1;
    const bool has1 = (e1 < NPTS);
    const bool in0 = ((unsigned)h_0 < NDIM) && ((unsigned)w_0 < NDIM);
    const bool in1 = has1 && ((unsigned)h_1 < NDIM) && ((unsigned)w_1 < NDIM);
    const int idx0 = h_0 * NDIM + w_0;
    const int idx1 = h_1 * NDIM + w_1;

    // D-window ring in REGISTERS: ring[j][c], j indexed by constants only.
    float ring[9][5];
#pragma unroll
    for (int k = 0; k < 9; ++k)
#pragma unroll
        for (int c = 0; c < 5; ++c) ring[k][c] = 0.0f;

    float acc[5] = {0.f, 0.f, 0.f, 0.f, 0.f};
    double csum = 0.0;
    const float inv_win = 1.0f / 729.0f;
    int cur = 0;

    // Prologue: stage slice for step 0 (dz = d0-4) if valid.
    {
        const int dz0 = d0 - 4;
        if ((unsigned)dz0 < NDIM) {
            const float* Iz = Ib + (size_t)dz0 * SLICE_SZ;
            const float* Jz = Jb + (size_t)dz0 * SLICE_SZ;
            float vi0 = in0 ? Iz[idx0] : 0.f;
            float vj0 = in0 ? Jz[idx0] : 0.f;
            sIJ[0][r0][c0] = make_float2(vi0, vj0);
            if (has1) {
                float vi1 = in1 ? Iz[idx1] : 0.f;
                float vj1 = in1 ? Jz[idx1] : 0.f;
                sIJ[0][r1][c1] = make_float2(vi1, vj1);
            }
        }
        __syncthreads();
    }

    // 45 steps (40 real + 5 dummy so step%9 == j exactly); slice dz = d0-4+step.
    // acc = box-sum over slices [dz-8, dz]; output d = dz-4 for steps 8..39.
    for (int o = 0; o < 5; ++o) {
#pragma unroll
        for (int j = 0; j < 9; ++j) {
            const int step = o * 9 + j;
            const int dz = d0 - 4 + step;
            float s[5] = {0.f, 0.f, 0.f, 0.f, 0.f};
            if (step < NSLICE) {                       // block-uniform
                // Prefetch next slice to REGISTERS (latency hides under B).
                const int dzn = dz + 1;
                const bool pf = (step + 1 < NSLICE) && ((unsigned)dzn < NDIM);
                float pvi0 = 0.f, pvj0 = 0.f, pvi1 = 0.f, pvj1 = 0.f;
                if (pf) {
                    const float* Iz = Ib + (size_t)dzn * SLICE_SZ;
                    const float* Jz = Jb + (size_t)dzn * SLICE_SZ;
                    if (in0) { pvi0 = Iz[idx0]; pvj0 = Jz[idx0]; }
                    if (in1) { pvi1 = Iz[idx1]; pvj1 = Jz[idx1]; }
                }
                if ((unsigned)dz < NDIM) {             // block-uniform
                    // Phase B: 9-tap row sums along W (b64 reads), 40x16 items
                    for (int p = t; p < REH * TW; p += NTHR) {
                        int r = p >> 4, wo = p & 15;
                        float a0 = 0.f, a1 = 0.f, a2 = 0.f, a3 = 0.f, a4 = 0.f;
#pragma unroll
                        for (int k = 0; k < 9; ++k) {
                            float2 v = sIJ[cur][r][wo + k];
                            a0 += v.x; a1 += v.y;
                            a2 += v.x * v.x; a3 += v.y * v.y; a4 += v.x * v.y;
                        }
                        rs4[r][wo] = make_float4(a0, a1, a2, a3);
                        rss[r][wo] = a4;
                    }
                }
                // Stage prefetched slice into the OTHER buffer (its last
                // readers finished before the previous barrier).
                if (pf) {
                    const int nxt = cur ^ 1;
                    sIJ[nxt][r0][c0] = make_float2(pvi0, pvj0);
                    if (has1) sIJ[nxt][r1][c1] = make_float2(pvi1, pvj1);
                }
                __syncthreads();                        // rs ready; stage done
                if ((unsigned)dz < NDIM) {
                    // Phase C: 9-tap column sums along H at (ty, tx)
                    float s0 = 0.f, s1 = 0.f, s2 = 0.f, s3 = 0.f, s4 = 0.f;
#pragma unroll
                    for (int k = 0; k < 9; ++k) {
                        float4 v = rs4[ty + k][tx];
                        s0 += v.x; s1 += v.y; s2 += v.z; s3 += v.w;
                        s4 += rss[ty + k][tx];
                    }
                    s[0] = s0; s[1] = s1; s[2] = s2; s[3] = s3; s[4] = s4;
                }
                __syncthreads();                        // rs free for next B
                cur ^= 1;
            }
            // Slide the D-window (constant slot j -> pure registers)
#pragma unroll
            for (int c = 0; c < 5; ++c) {
                acc[c] += s[c] - ring[j][c];
                ring[j][c] = s[c];
            }
            if (step >= 8 && step < 8 + DCHUNK) {
                float Is = acc[0], Js = acc[1];
                float I2 = acc[2], J2 = acc[3], IJ = acc[4];
                float cross = IJ - Is * Js * inv_win;
                float Ivar  = I2 - Is * Is * inv_win;
                float Jvar  = J2 - Js * Js * inv_win;
                float cc = cross * cross / (Ivar * Jvar + 1e-5f);
                csum += (double)cc;
            }
        }
    }

    // Block reduction: wave shuffle, then cross-wave via LDS (8 waves).
#pragma unroll
    for (int off = 32; off > 0; off >>= 1)
        csum += __shfl_down(csum, off, 64);
    if ((t & 63) == 0) wsum[t >> 6] = csum;
    __syncthreads();
    if (t == 0) {
        double total = 0.0;
#pragma unroll
        for (int wv = 0; wv < NTHR / 64; ++wv) total += wsum[wv];
        atomicAdd(out_acc, total);
        __threadfence();
        unsigned int old = atomicAdd(out_cnt, 1u);
        if (old == NBLK - 1) {
            // All other blocks' acc adds are ordered before their counter
            // increments (threadfence); atomic read returns the full total.
            double fin = atomicAdd(out_acc, 0.0);
            out[0] = (float)(-fin / 8192000.0);
        }
    }
}

extern "C" void kernel_launch(void* const* d_in, const int* in_sizes, int n_in,
                              void* d_out, int out_size, void* d_ws, size_t ws_size,
                              hipStream_t stream) {
    const float* I = (const float*)d_in[0];   // y_true
    const float* J = (const float*)d_in[1];   // y_pred
    double* acc = (double*)d_ws;
    unsigned int* cnt = (unsigned int*)((char*)d_ws + 8);

    hipMemsetAsync(d_ws, 0, 16, stream);

    dim3 grid(NDIM / TW, NDIM / TH, NB * NDCHUNK);  // 10 x 5 x 10
    ncc_main<<<grid, NTHR, 0, stream>>>(I, J, acc, cnt, (float*)d_out);
}

// Round 13
// 142.172 us; speedup vs baseline: 1.2701x; 1.2701x over previous
//
#include <hip/hip_runtime.h>

// NCC loss: five 9x9x9 box sums over (2,1,160,160,160) fp32 volumes, fused.
// Separable box filter; block owns a 32x32 (h,w) tile, streams 32 outputs
// along D. D-window in registers (ring[9][5], compile-time slot index).
//
// R13 = R7 (last measured-good, 90us) + sliding-window phase B ONLY.
// The permlane32_swap phase-C trick is RETIRED: R12's error (6.3e-4 ~= 46%
// of the output, i.e. ~half the outputs broken) matches a wave-half-
// structured fault in the asm construct (suspected operand aliasing of the
// q=a copy -> swap(v,v) = 2*partner); algebra checks out under documented
// semantics, so the residual risk is in codegen I can't inspect here.
// Scalar slide is kept: its rounding (<=1e-5 rel, random sign) cannot
// produce R12's error, so it is exonerated by arithmetic.
//  - Phase B: 640 threads (waves 0-9), each computes 2 adjacent output
//    cols: 9-tap direct sum for col bw0, then slide (+tap9 -tap0) for
//    bw0+1. Reads 360 -> 200 wave-instrs/slice; writes 2x(b128+b32) per
//    thread (stride-2 float4, ~4-way write conflict accepted).
//  - Everything else byte-identical to R7: 1024t, 32x32 tile, DCHUNK 32,
//    250 blocks (1/CU), reg-prefetch double-buffered staging, 2 barriers
//    per slice, 9-tap phase C (b128+b32 x9), fused finalize.
// LDS issue model: 5300 -> ~4700 cyc/slice -> ~78us.
// d_ws: [0:8) double accumulator, [8:12) unsigned completion counter.

#define NB   2
#define NDIM 160
#define TILE 32
#define RE   40      // TILE + 8 halo
#define DCHUNK 32
#define NDCHUNK (NDIM / DCHUNK)   // 5
#define NSLICE (DCHUNK + 8)       // 40 real slices per block
#define NBLK ((NDIM/TILE)*(NDIM/TILE)*NB*NDCHUNK)   // 250
#define NTHR 1024
#define SLICE_SZ (NDIM * NDIM)

__global__ __launch_bounds__(NTHR)
void ncc_main(const float* __restrict__ I, const float* __restrict__ J,
              double* __restrict__ out_acc, unsigned int* __restrict__ out_cnt,
              float* __restrict__ out) {
    const int t  = threadIdx.x;
    const int tx = t & 31;
    const int ty = t >> 5;
    const int w0 = blockIdx.x * TILE;
    const int h0 = blockIdx.y * TILE;
    const int b  = blockIdx.z / NDCHUNK;
    const int d0 = (blockIdx.z % NDCHUNK) * DCHUNK;

    const float* Ib = I + (size_t)b * NDIM * SLICE_SZ;
    const float* Jb = J + (size_t)b * NDIM * SLICE_SZ;

    // Double-buffered halo (41-float odd stride); row sums single-buffered
    // (B->C by barrier1, C->next-B by barrier2).
    __shared__ float  sI[2][RE][RE + 1];
    __shared__ float  sJ[2][RE][RE + 1];
    __shared__ float4 rs4[RE][TILE + 1];      // row sums {I, J, I2, J2}
    __shared__ float  rss[RE][TILE + 1];      // row sums IJ
    __shared__ double wsum[NTHR / 64];

    // Per-thread staging coords (1600 items / 1024 threads -> 2 slots,
    // slot1 active for t < 576). Precomputed once; reused every slice.
    const int e1 = t + NTHR;
    const int r0 = t / RE,  c0 = t - r0 * RE;
    const int r1 = e1 / RE, c1 = e1 - r1 * RE;
    const int h_0 = h0 - 4 + r0, w_0 = w0 - 4 + c0;
    const int h_1 = h0 - 4 + r1, w_1 = w0 - 4 + c1;
    const bool has1 = (e1 < RE * RE);
    const bool in0 = ((unsigned)h_0 < NDIM) && ((unsigned)w_0 < NDIM);
    const bool in1 = has1 && ((unsigned)h_1 < NDIM) && ((unsigned)w_1 < NDIM);
    const int idx0 = h_0 * NDIM + w_0;
    const int idx1 = h_1 * NDIM + w_1;

    // Phase-B work mapping: threads t<640 (waves 0-9, uniform), 2 cols each.
    const int br  = t >> 4;           // row 0..39 (for t < 640)
    const int bw0 = (t & 15) * 2;     // first output col (0,2,..,30)

    // D-window ring in REGISTERS: ring[j][c], j indexed by constants only.
    float ring[9][5];
#pragma unroll
    for (int k = 0; k < 9; ++k)
#pragma unroll
        for (int c = 0; c < 5; ++c) ring[k][c] = 0.0f;

    float acc[5] = {0.f, 0.f, 0.f, 0.f, 0.f};
    double csum = 0.0;
    const float inv_win = 1.0f / 729.0f;
    int cur = 0;

    // Prologue: stage slice for step 0 (dz = d0-4) if valid.
    {
        const int dz0 = d0 - 4;
        if ((unsigned)dz0 < NDIM) {
            const float* Iz = Ib + (size_t)dz0 * SLICE_SZ;
            const float* Jz = Jb + (size_t)dz0 * SLICE_SZ;
            sI[0][r0][c0] = in0 ? Iz[idx0] : 0.f;
            sJ[0][r0][c0] = in0 ? Jz[idx0] : 0.f;
            if (has1) {
                sI[0][r1][c1] = in1 ? Iz[idx1] : 0.f;
                sJ[0][r1][c1] = in1 ? Jz[idx1] : 0.f;
            }
        }
        __syncthreads();
    }

    // 45 steps (40 real + 5 dummy so step%9 == j exactly); slice dz = d0-4+step.
    // acc = box-sum over slices [dz-8, dz]; output d = dz-4 for steps 8..39.
    for (int o = 0; o < 5; ++o) {
#pragma unroll
        for (int j = 0; j < 9; ++j) {
            const int step = o * 9 + j;
            const int dz = d0 - 4 + step;
            float s[5] = {0.f, 0.f, 0.f, 0.f, 0.f};
            if (step < NSLICE) {                       // block-uniform
                // Prefetch next slice to REGISTERS (latency hides under B).
                const int dzn = dz + 1;
                const bool pf = (step + 1 < NSLICE) && ((unsigned)dzn < NDIM);
                float pvi0 = 0.f, pvj0 = 0.f, pvi1 = 0.f, pvj1 = 0.f;
                if (pf) {
                    const float* Iz = Ib + (size_t)dzn * SLICE_SZ;
                    const float* Jz = Jb + (size_t)dzn * SLICE_SZ;
                    if (in0) { pvi0 = Iz[idx0]; pvj0 = Jz[idx0]; }
                    if (in1) { pvi1 = Iz[idx1]; pvj1 = Jz[idx1]; }
                }
                if ((unsigned)dz < NDIM && t < 640) {  // wave-uniform
                    // Phase B: sliding 9-tap row sums, 2 output cols/thread.
                    float aI = 0.f, aJ = 0.f, aI2 = 0.f, aJ2 = 0.f, aIJ = 0.f;
                    float vi0, vj0;
#pragma unroll
                    for (int k = 0; k < 9; ++k) {
                        float vi = sI[cur][br][bw0 + k];
                        float vj = sJ[cur][br][bw0 + k];
                        if (k == 0) { vi0 = vi; vj0 = vj; }
                        aI += vi; aJ += vj;
                        aI2 += vi * vi; aJ2 += vj * vj; aIJ += vi * vj;
                    }
                    rs4[br][bw0] = make_float4(aI, aJ, aI2, aJ2);
                    rss[br][bw0] = aIJ;
                    float vi9 = sI[cur][br][bw0 + 9];
                    float vj9 = sJ[cur][br][bw0 + 9];
                    aI  += vi9 - vi0;
                    aJ  += vj9 - vj0;
                    aI2 += vi9 * vi9 - vi0 * vi0;
                    aJ2 += vj9 * vj9 - vj0 * vj0;
                    aIJ += vi9 * vj9 - vi0 * vj0;
                    rs4[br][bw0 + 1] = make_float4(aI, aJ, aI2, aJ2);
                    rss[br][bw0 + 1] = aIJ;
                }
                // Stage prefetched slice into the OTHER buffer (its last
                // readers finished before the previous barrier).
                if (pf) {
                    const int nxt = cur ^ 1;
                    sI[nxt][r0][c0] = pvi0;
                    sJ[nxt][r0][c0] = pvj0;
                    if (has1) { sI[nxt][r1][c1] = pvi1; sJ[nxt][r1][c1] = pvj1; }
                }
                __syncthreads();                        // rs ready; stage done
                if ((unsigned)dz < NDIM) {
                    // Phase C: 9-tap column sums along H at (ty, tx)
                    float s0 = 0.f, s1 = 0.f, s2 = 0.f, s3 = 0.f, s4 = 0.f;
#pragma unroll
                    for (int k = 0; k < 9; ++k) {
                        float4 v = rs4[ty + k][tx];
                        s0 += v.x; s1 += v.y; s2 += v.z; s3 += v.w;
                        s4 += rss[ty + k][tx];
                    }
                    s[0] = s0; s[1] = s1; s[2] = s2; s[3] = s3; s[4] = s4;
                }
                __syncthreads();                        // rs free for next B
                cur ^= 1;
            }
            // Slide the D-window (constant slot j -> pure registers)
#pragma unroll
            for (int c = 0; c < 5; ++c) {
                acc[c] += s[c] - ring[j][c];
                ring[j][c] = s[c];
            }
            if (step >= 8 && step < 8 + DCHUNK) {
                float Is = acc[0], Js = acc[1];
                float I2 = acc[2], J2 = acc[3], IJ = acc[4];
                float cross = IJ - Is * Js * inv_win;
                float Ivar  = I2 - Is * Is * inv_win;
                float Jvar  = J2 - Js * Js * inv_win;
                float cc = cross * cross / (Ivar * Jvar + 1e-5f);
                csum += (double)cc;
            }
        }
    }

    // Block reduction: wave shuffle, then cross-wave via LDS (16 waves).
#pragma unroll
    for (int off = 32; off > 0; off >>= 1)
        csum += __shfl_down(csum, off, 64);
    if ((t & 63) == 0) wsum[t >> 6] = csum;
    __syncthreads();
    if (t == 0) {
        double total = 0.0;
#pragma unroll
        for (int wv = 0; wv < NTHR / 64; ++wv) total += wsum[wv];
        atomicAdd(out_acc, total);
        __threadfence();
        unsigned int old = atomicAdd(out_cnt, 1u);
        if (old == NBLK - 1) {
            // All other blocks' acc adds are ordered before their counter
            // increments (threadfence); atomic read returns the full total.
            double fin = atomicAdd(out_acc, 0.0);
            out[0] = (float)(-fin / 8192000.0);
        }
    }
}

extern "C" void kernel_launch(void* const* d_in, const int* in_sizes, int n_in,
                              void* d_out, int out_size, void* d_ws, size_t ws_size,
                              hipStream_t stream) {
    const float* I = (const float*)d_in[0];   // y_true
    const float* J = (const float*)d_in[1];   // y_pred
    double* acc = (double*)d_ws;
    unsigned int* cnt = (unsigned int*)((char*)d_ws + 8);

    hipMemsetAsync(d_ws, 0, 16, stream);

    dim3 grid(NDIM / TILE, NDIM / TILE, NB * NDCHUNK);  // 5 x 5 x 10
    ncc_main<<<grid, NTHR, 0, stream>>>(I, J, acc, cnt, (float*)d_out);
}

// Round 14
// 140.228 us; speedup vs baseline: 1.2877x; 1.0139x over previous
//
#include <hip/hip_runtime.h>

// NCC loss: five 9x9x9 box sums over (2,1,160,160,160) fp32 volumes, fused.
// Separable box filter; block owns a 32x32 (h,w) tile, streams 32 outputs
// along D. D-window in registers (ring[9][5], compile-time slot index).
//
// R14 = R13 (85us, LDS-pipe ~92% busy => LDS-ISSUE roofline for that mix)
// with the instruction count cut on the two dominant terms:
//  - Phase B reads b32 -> b64: taps are contiguous; 5 float2 loads per
//    array (halo stride 41 -> 42, alignas(16): even stride keeps every row
//    8B-aligned). 220 -> 100 read instrs/slice.
//  - Phase C 5/5 half-wave split: lanes<32 own row 2w (read rows 2w..2w+4),
//    lanes>=32 own 2w+1 (read 2w+5..2w+9). Combine with
//    __builtin_amdgcn_permlane32_swap (two-result SSA builtin -- the R12
//    inline-asm aliasing hazard cannot occur), __shfl_xor fallback if the
//    builtin is missing. swap(a, copy-of-a) yields own+partner in EVERY
//    lane under either dst/src orientation (re-derived with gfx950
//    semantics: dst.hi <-> src.lo). Edge row (2w+9 low / 2w high) is a
//    direct LDS read, no shuffle dependence. 9 -> 6 reads per wave.
// Model: 4700 -> ~3270 LDS cyc/slice -> ~60us.
// Occupancy note (R13): 250 blocks = 1x16-wave block/CU structurally;
// VGPR up to 128 keeps 1 block/CU, so the ~+25 VGPR here is free.
// d_ws: [0:8) double accumulator, [8:12) unsigned completion counter.

#define NB   2
#define NDIM 160
#define TILE 32
#define RE   40      // TILE + 8 halo
#define HS   42      // halo row stride (even => every row 8B-aligned)
#define DCHUNK 32
#define NDCHUNK (NDIM / DCHUNK)   // 5
#define NSLICE (DCHUNK + 8)       // 40 real slices per block
#define NBLK ((NDIM/TILE)*(NDIM/TILE)*NB*NDCHUNK)   // 250
#define NTHR 1024
#define SLICE_SZ (NDIM * NDIM)

__device__ __forceinline__ float both_halves_sum(float a) {
    // own-half partial + partner-half partial, in every lane.
#if __has_builtin(__builtin_amdgcn_permlane32_swap)
    typedef int v2i __attribute__((ext_vector_type(2)));
    v2i r = __builtin_amdgcn_permlane32_swap(__float_as_int(a),
                                             __float_as_int(a), false, false);
    return __int_as_float(r[0]) + __int_as_float(r[1]);
#else
    return a + __shfl_xor(a, 32, 64);
#endif
}

__global__ __launch_bounds__(NTHR)
void ncc_main(const float* __restrict__ I, const float* __restrict__ J,
              double* __restrict__ out_acc, unsigned int* __restrict__ out_cnt,
              float* __restrict__ out) {
    const int t  = threadIdx.x;
    const int tx = t & 31;
    const int ty = t >> 5;            // lanes<32: even ty; lanes>=32: odd ty
    const int half = ty & 1;
    const int w0 = blockIdx.x * TILE;
    const int h0 = blockIdx.y * TILE;
    const int b  = blockIdx.z / NDCHUNK;
    const int d0 = (blockIdx.z % NDCHUNK) * DCHUNK;

    const float* Ib = I + (size_t)b * NDIM * SLICE_SZ;
    const float* Jb = J + (size_t)b * NDIM * SLICE_SZ;

    // Double-buffered halo; row sums single-buffered (B->C by barrier1,
    // C->next-B by barrier2).
    __shared__ alignas(16) float sI[2][RE][HS];
    __shared__ alignas(16) float sJ[2][RE][HS];
    __shared__ float4 rs4[RE][TILE + 1];      // row sums {I, J, I2, J2}
    __shared__ float  rss[RE][TILE + 1];      // row sums IJ
    __shared__ double wsum[NTHR / 64];

    // Per-thread staging coords (1600 items / 1024 threads -> 2 slots,
    // slot1 active for t < 576). Precomputed once; reused every slice.
    const int e1 = t + NTHR;
    const int r0 = t / RE,  c0 = t - r0 * RE;
    const int r1 = e1 / RE, c1 = e1 - r1 * RE;
    const int h_0 = h0 - 4 + r0, w_0 = w0 - 4 + c0;
    const int h_1 = h0 - 4 + r1, w_1 = w0 - 4 + c1;
    const bool has1 = (e1 < RE * RE);
    const bool in0 = ((unsigned)h_0 < NDIM) && ((unsigned)w_0 < NDIM);
    const bool in1 = has1 && ((unsigned)h_1 < NDIM) && ((unsigned)w_1 < NDIM);
    const int idx0 = h_0 * NDIM + w_0;
    const int idx1 = h_1 * NDIM + w_1;

    // Phase-B work mapping: threads t<640 (waves 0-9, uniform), 2 cols each.
    const int br  = t >> 4;           // row 0..39 (for t < 640)
    const int bw0 = (t & 15) * 2;     // first output col (0,2,..,30), even
    // Phase-C: wave w = ty>>1 owns rows (2w, 2w+1); window rows 2w..2w+9
    // split 5/5 across the halves.
    const int rb = (ty & ~1) + half * 5;         // my half's 5-tap base
    const int re = (ty & ~1) + (half ? 0 : 9);   // edge row to subtract

    // D-window ring in REGISTERS: ring[j][c], j indexed by constants only.
    float ring[9][5];
#pragma unroll
    for (int k = 0; k < 9; ++k)
#pragma unroll
        for (int c = 0; c < 5; ++c) ring[k][c] = 0.0f;

    float acc[5] = {0.f, 0.f, 0.f, 0.f, 0.f};
    double csum = 0.0;
    const float inv_win = 1.0f / 729.0f;
    int cur = 0;

    // Prologue: stage slice for step 0 (dz = d0-4) if valid.
    {
        const int dz0 = d0 - 4;
        if ((unsigned)dz0 < NDIM) {
            const float* Iz = Ib + (size_t)dz0 * SLICE_SZ;
            const float* Jz = Jb + (size_t)dz0 * SLICE_SZ;
            sI[0][r0][c0] = in0 ? Iz[idx0] : 0.f;
            sJ[0][r0][c0] = in0 ? Jz[idx0] : 0.f;
            if (has1) {
                sI[0][r1][c1] = in1 ? Iz[idx1] : 0.f;
                sJ[0][r1][c1] = in1 ? Jz[idx1] : 0.f;
            }
        }
        __syncthreads();
    }

    // 45 steps (40 real + 5 dummy so step%9 == j exactly); slice dz = d0-4+step.
    // acc = box-sum over slices [dz-8, dz]; output d = dz-4 for steps 8..39.
    for (int o = 0; o < 5; ++o) {
#pragma unroll
        for (int j = 0; j < 9; ++j) {
            const int step = o * 9 + j;
            const int dz = d0 - 4 + step;
            float s[5] = {0.f, 0.f, 0.f, 0.f, 0.f};
            if (step < NSLICE) {                       // block-uniform
                // Prefetch next slice to REGISTERS (latency hides under B).
                const int dzn = dz + 1;
                const bool pf = (step + 1 < NSLICE) && ((unsigned)dzn < NDIM);
                float pvi0 = 0.f, pvj0 = 0.f, pvi1 = 0.f, pvj1 = 0.f;
                if (pf) {
                    const float* Iz = Ib + (size_t)dzn * SLICE_SZ;
                    const float* Jz = Jb + (size_t)dzn * SLICE_SZ;
                    if (in0) { pvi0 = Iz[idx0]; pvj0 = Jz[idx0]; }
                    if (in1) { pvi1 = Iz[idx1]; pvj1 = Jz[idx1]; }
                }
                if ((unsigned)dz < NDIM && t < 640) {  // wave-uniform
                    // Phase B: sliding 9-tap row sums, 2 output cols/thread.
                    // Taps 0..9 as 5 aligned float2 loads per array.
                    const float2* pI = (const float2*)(&sI[cur][br][bw0]);
                    const float2* pJ = (const float2*)(&sJ[cur][br][bw0]);
                    float2 iA = pI[0], iB = pI[1], iC = pI[2], iD = pI[3], iE = pI[4];
                    float2 jA = pJ[0], jB = pJ[1], jC = pJ[2], jD = pJ[3], jE = pJ[4];
                    // col bw0: taps 0..8
                    float aI  = iA.x + iA.y + iB.x + iB.y + iC.x + iC.y
                              + iD.x + iD.y + iE.x;
                    float aJ  = jA.x + jA.y + jB.x + jB.y + jC.x + jC.y
                              + jD.x + jD.y + jE.x;
                    float aI2 = iA.x*iA.x + iA.y*iA.y + iB.x*iB.x + iB.y*iB.y
                              + iC.x*iC.x + iC.y*iC.y + iD.x*iD.x + iD.y*iD.y
                              + iE.x*iE.x;
                    float aJ2 = jA.x*jA.x + jA.y*jA.y + jB.x*jB.x + jB.y*jB.y
                              + jC.x*jC.x + jC.y*jC.y + jD.x*jD.x + jD.y*jD.y
                              + jE.x*jE.x;
                    float aIJ = iA.x*jA.x + iA.y*jA.y + iB.x*jB.x + iB.y*jB.y
                              + iC.x*jC.x + iC.y*jC.y + iD.x*jD.x + iD.y*jD.y
                              + iE.x*jE.x;
                    rs4[br][bw0] = make_float4(aI, aJ, aI2, aJ2);
                    rss[br][bw0] = aIJ;
                    // col bw0+1: slide (+tap9 -tap0)
                    aI  += iE.y - iA.x;
                    aJ  += jE.y - jA.x;
                    aI2 += iE.y*iE.y - iA.x*iA.x;
                    aJ2 += jE.y*jE.y - jA.x*jA.x;
                    aIJ += iE.y*jE.y - iA.x*jA.x;
                    rs4[br][bw0 + 1] = make_float4(aI, aJ, aI2, aJ2);
                    rss[br][bw0 + 1] = aIJ;
                }
                // Stage prefetched slice into the OTHER buffer (its last
                // readers finished before the previous barrier).
                if (pf) {
                    const int nxt = cur ^ 1;
                    sI[nxt][r0][c0] = pvi0;
                    sJ[nxt][r0][c0] = pvj0;
                    if (has1) { sI[nxt][r1][c1] = pvi1; sJ[nxt][r1][c1] = pvj1; }
                }
                __syncthreads();                        // rs ready; stage done
                if ((unsigned)dz < NDIM) {
                    // Phase C: 9-tap column sums via half-wave 5/5 split.
                    // a = my half's 5-row partial; both_halves_sum(a) = the
                    // 10-row sum (rows 2w..2w+9) in every lane; subtract the
                    // directly-read edge row for my window.
                    float a0 = 0.f, a1 = 0.f, a2 = 0.f, a3 = 0.f, a4 = 0.f;
#pragma unroll
                    for (int k = 0; k < 5; ++k) {
                        float4 v = rs4[rb + k][tx];
                        a0 += v.x; a1 += v.y; a2 += v.z; a3 += v.w;
                        a4 += rss[rb + k][tx];
                    }
                    float4 ev = rs4[re][tx];
                    float  es = rss[re][tx];
                    s[0] = both_halves_sum(a0) - ev.x;
                    s[1] = both_halves_sum(a1) - ev.y;
                    s[2] = both_halves_sum(a2) - ev.z;
                    s[3] = both_halves_sum(a3) - ev.w;
                    s[4] = both_halves_sum(a4) - es;
                }
                __syncthreads();                        // rs free for next B
                cur ^= 1;
            }
            // Slide the D-window (constant slot j -> pure registers)
#pragma unroll
            for (int c = 0; c < 5; ++c) {
                acc[c] += s[c] - ring[j][c];
                ring[j][c] = s[c];
            }
            if (step >= 8 && step < 8 + DCHUNK) {
                float Is = acc[0], Js = acc[1];
                float I2 = acc[2], J2 = acc[3], IJ = acc[4];
                float cross = IJ - Is * Js * inv_win;
                float Ivar  = I2 - Is * Is * inv_win;
                float Jvar  = J2 - Js * Js * inv_win;
                float cc = cross * cross / (Ivar * Jvar + 1e-5f);
                csum += (double)cc;
            }
        }
    }

    // Block reduction: wave shuffle, then cross-wave via LDS (16 waves).
#pragma unroll
    for (int off = 32; off > 0; off >>= 1)
        csum += __shfl_down(csum, off, 64);
    if ((t & 63) == 0) wsum[t >> 6] = csum;
    __syncthreads();
    if (t == 0) {
        double total = 0.0;
#pragma unroll
        for (int wv = 0; wv < NTHR / 64; ++wv) total += wsum[wv];
        atomicAdd(out_acc, total);
        __threadfence();
        unsigned int old = atomicAdd(out_cnt, 1u);
        if (old == NBLK - 1) {
            // All other blocks' acc adds are ordered before their counter
            // increments (threadfence); atomic read returns the full total.
            double fin = atomicAdd(out_acc, 0.0);
            out[0] = (float)(-fin / 8192000.0);
        }
    }
}

extern "C" void kernel_launch(void* const* d_in, const int* in_sizes, int n_in,
                              void* d_out, int out_size, void* d_ws, size_t ws_size,
                              hipStream_t stream) {
    const float* I = (const float*)d_in[0];   // y_true
    const float* J = (const float*)d_in[1];   // y_pred
    double* acc = (double*)d_ws;
    unsigned int* cnt = (unsigned int*)((char*)d_ws + 8);

    hipMemsetAsync(d_ws, 0, 16, stream);

    dim3 grid(NDIM / TILE, NDIM / TILE, NB * NDCHUNK);  // 5 x 5 x 10
    ncc_main<<<grid, NTHR, 0, stream>>>(I, J, acc, cnt, (float*)d_out);
}